// Round 14
// baseline (352.420 us; speedup 1.0000x reference)
//
#include <hip/hip_runtime.h>
#include <math.h>

#define HD   128
#define EFD  16
#define MT   64      // node-kernel tile
#define WT   16      // edges per WAVE tile (edge kernel)
#define LPA  264
#define LPC  136     // node kernels keep old pitch
#define LPW  132     // wave-local activation pitch (ushort)

#define W1SZ (128 * 288)
#define W2SZ (128 * 128)
#define O_WE1 (W1SZ)
#define O_WC2 (2 * W1SZ)
#define O_WE2 (2 * W1SZ + W2SZ)
#define O_WN1 (2 * W1SZ + 2 * W2SZ)
#define O_WN2 (2 * W1SZ + 2 * W2SZ + 128 * 256)
#define WS_ELEMS (O_WN2 + W2SZ)          // 155648

// ws byte layout (~40.4 MB)
#define B_PSC   ((size_t)0)
#define B_PDC   ((size_t)8388608)
#define B_PSE   ((size_t)16777216)
#define B_PDE   ((size_t)25165824)
#define B_WPAN  ((size_t)33554432)
#define B_CNT   ((size_t)33865728)
#define B_OFS   ((size_t)33996800)
#define B_SRCP  ((size_t)34127872)
#define B_DSTP  ((size_t)36225024)
#define B_EIDX  ((size_t)38322176)

typedef __attribute__((ext_vector_type(8))) short short8;
typedef __attribute__((ext_vector_type(4))) float f32x4;

__device__ __forceinline__ unsigned short f2bf(float x) {
    __bf16 b = (__bf16)x;
    unsigned short u;
    __builtin_memcpy(&u, &b, 2);
    return u;
}
__device__ __forceinline__ float bfl(unsigned u) {
    union { unsigned u; float f; } v; v.u = u << 16; return v.f;
}
__device__ __forceinline__ float bfh(unsigned u) {
    union { unsigned u; float f; } v; v.u = u & 0xffff0000u; return v.f;
}
__device__ __forceinline__ float sigm_f(float x) {
    return __builtin_amdgcn_rcpf(1.f + __expf(-x));
}
__device__ __forceinline__ float silu_f(float x) { return x * sigm_f(x); }
__device__ __forceinline__ unsigned pack2(float a, float b) {
    return (unsigned)f2bf(a) | ((unsigned)f2bf(b) << 16);
}

// ---------------------------------------------------------------------------
// Fragment-ordered bf16 weight panels (A-operand layout).
// ---------------------------------------------------------------------------
__device__ __forceinline__ void frag_l1(int idx, const float* __restrict__ W,
                                        const float* __restrict__ bias,
                                        unsigned short* __restrict__ out)
{
    const int j = idx & 7, lane = (idx >> 3) & 63, blk = idx >> 9;
    const int kc = blk % 9, n = blk / 9;
    const int k = kc * 32 + (lane >> 4) * 8 + j;
    const int c = n * 16 + (lane & 15);
    float v = 0.f;
    if (k < 256) v = W[k * HD + c];
    else if (k < 272) v = W[(k + 1) * HD + c];
    else if (k == 272) v = W[256 * HD + c];
    else if (k == 273) v = bias[c];
    out[idx] = f2bf(v);
}
__device__ __forceinline__ void frag_sq(int idx, const float* __restrict__ W,
                                        int nkc, unsigned short* __restrict__ out)
{
    const int j = idx & 7, lane = (idx >> 3) & 63, blk = idx >> 9;
    const int kc = blk % nkc, n = blk / nkc;
    const int k = kc * 32 + (lane >> 4) * 8 + j;
    const int c = n * 16 + (lane & 15);
    out[idx] = f2bf(W[k * HD + c]);
}

__global__ __launch_bounds__(256) void fused_prep(
    const float* __restrict__ Wc1, const float* __restrict__ bc1,
    const float* __restrict__ We1, const float* __restrict__ be1,
    const float* __restrict__ Wc2, const float* __restrict__ We2,
    const float* __restrict__ Wn1, const float* __restrict__ Wn2,
    unsigned short* __restrict__ ws,
    const int* __restrict__ dst, unsigned* __restrict__ cnt,
    int nPrep, int E)
{
    const int bid = blockIdx.x, tid = threadIdx.x;
    if (bid < nPrep) {
        int idx = bid * 256 + tid;
        if (idx < W1SZ)            { frag_l1(idx, Wc1, bc1, ws);            return; }
        idx -= W1SZ;
        if (idx < W1SZ)            { frag_l1(idx, We1, be1, ws + O_WE1);    return; }
        idx -= W1SZ;
        if (idx < W2SZ)            { frag_sq(idx, Wc2, 4, ws + O_WC2);      return; }
        idx -= W2SZ;
        if (idx < W2SZ)            { frag_sq(idx, We2, 4, ws + O_WE2);      return; }
        idx -= W2SZ;
        if (idx < 128 * 256)       { frag_sq(idx, Wn1, 8, ws + O_WN1);      return; }
        idx -= 128 * 256;
        if (idx < W2SZ)            { frag_sq(idx, Wn2, 4, ws + O_WN2); }
        return;
    }
    const int i = (bid - nPrep) * 256 + tid;
    if (i < E) atomicAdd(&cnt[dst[i]], 1u);
}

// ---------------------------------------------------------------------------
// node_pre: P tables = h @ W1-halves
// ---------------------------------------------------------------------------
__device__ __forceinline__ void pre_pass(
    const unsigned short* __restrict__ panelp,
    const unsigned short* __restrict__ hsh,
    unsigned short* __restrict__ Ps, unsigned short* __restrict__ Pd,
    int n0, int w2, int w, int col, int kg)
{
    const f32x4 zero = {0.f, 0.f, 0.f, 0.f};
    f32x4 as_[2][4], ad_[2][4];
    #pragma unroll
    for (int m = 0; m < 2; ++m)
        #pragma unroll
        for (int et = 0; et < 4; ++et) { as_[m][et] = zero; ad_[m][et] = zero; }
    #pragma unroll
    for (int kc = 0; kc < 4; ++kc) {
        short8 bf[4];
        #pragma unroll
        for (int et = 0; et < 4; ++et)
            bf[et] = *(const short8*)&hsh[(et*16 + col) * LPC + kc * 32 + kg * 8];
        #pragma unroll
        for (int m = 0; m < 2; ++m) {
            const short8 As = *(const short8*)&panelp[((w2 + m) * 9 + kc) << 9];
            const short8 Ad = *(const short8*)&panelp[((w2 + m) * 9 + kc + 4) << 9];
            #pragma unroll
            for (int et = 0; et < 4; ++et) {
                as_[m][et] = __builtin_amdgcn_mfma_f32_16x16x32_bf16(As, bf[et], as_[m][et], 0, 0, 0);
                ad_[m][et] = __builtin_amdgcn_mfma_f32_16x16x32_bf16(Ad, bf[et], ad_[m][et], 0, 0, 0);
            }
        }
    }
    #pragma unroll
    for (int m = 0; m < 2; ++m)
        #pragma unroll
        for (int et = 0; et < 4; ++et) {
            const size_t row = (size_t)(n0 + et * 16 + col) * HD;
            const int hw = w * 32 + m * 16 + kg * 4;
            uint2 vs, vd;
            vs.x = pack2(as_[m][et][0], as_[m][et][1]);
            vs.y = pack2(as_[m][et][2], as_[m][et][3]);
            vd.x = pack2(ad_[m][et][0], ad_[m][et][1]);
            vd.y = pack2(ad_[m][et][2], ad_[m][et][3]);
            *(uint2*)(Ps + row + hw) = vs;
            *(uint2*)(Pd + row + hw) = vd;
        }
}

__global__ __launch_bounds__(256) void node_pre(
    const float* __restrict__ h, const unsigned short* __restrict__ wpan,
    unsigned short* __restrict__ Psc, unsigned short* __restrict__ Pdc,
    unsigned short* __restrict__ Pse, unsigned short* __restrict__ Pde)
{
    __shared__ __align__(16) unsigned short hsh[MT][LPC];
    const int tid = threadIdx.x;
    const int n0  = blockIdx.x * MT;

    #pragma unroll
    for (int it = 0; it < 8; ++it) {
        const int idx = it * 256 + tid;
        const int r = idx >> 5, q = idx & 31;
        const float4 v = *(const float4*)(h + (size_t)(n0 + r) * HD + q * 4);
        uint2 p; p.x = pack2(v.x, v.y); p.y = pack2(v.z, v.w);
        *(uint2*)&hsh[r][q * 4] = p;
    }
    __syncthreads();

    const int lane = tid & 63;
    const int w    = tid >> 6;
    const int w2   = w * 2;
    const int col  = lane & 15;
    const int kg   = lane >> 4;

    pre_pass(wpan + lane * 8,         &hsh[0][0], Psc, Pdc, n0, w2, w, col, kg);
    pre_pass(wpan + O_WE1 + lane * 8, &hsh[0][0], Pse, Pde, n0, w2, w, col, kg);
}

// ---------------------------------------------------------------------------
__global__ __launch_bounds__(1024) void scan32k(const unsigned* __restrict__ cnt,
                                                unsigned* __restrict__ ofs)
{
    __shared__ unsigned wsum[16];
    __shared__ unsigned carry_s;
    const int tid = threadIdx.x, lane = tid & 63, w = tid >> 6;
    if (tid == 0) carry_s = 0;
    __syncthreads();
    for (int c = 0; c < 32; ++c) {
        const unsigned x = cnt[c * 1024 + tid];
        unsigned v = x;
        #pragma unroll
        for (int off = 1; off < 64; off <<= 1) {
            unsigned t = __shfl_up(v, off);
            if (lane >= off) v += t;
        }
        if (lane == 63) wsum[w] = v;
        __syncthreads();
        if (tid < 16) {
            unsigned s = wsum[tid];
            #pragma unroll
            for (int off = 1; off < 16; off <<= 1) {
                unsigned t = __shfl_up(s, off);
                if (tid >= off) s += t;
            }
            wsum[tid] = s;
        }
        __syncthreads();
        const unsigned carry = carry_s;
        const unsigned woff = (w == 0) ? 0u : wsum[w - 1];
        ofs[c * 1024 + tid] = carry + woff + v - x;
        __syncthreads();
        if (tid == 0) carry_s = carry + wsum[15];
        __syncthreads();
    }
}

__global__ __launch_bounds__(256) void scatter_perm(
    const int* __restrict__ src, const int* __restrict__ dst,
    unsigned* __restrict__ ofs,
    int* __restrict__ srcp, int* __restrict__ dstp,
    int* __restrict__ eidx, int E)
{
    const int i = blockIdx.x * 256 + threadIdx.x;
    if (i >= E) return;
    const int d = dst[i];
    const unsigned pos = atomicAdd(&ofs[d], 1u);
    srcp[pos] = src[i];
    dstp[pos] = d;
    eidx[pos] = i;
}

// ---------------------------------------------------------------------------
// Edge kernel — WAVE-INDEPENDENT 16-edge tiles, ZERO __syncthreads.
// Each wave: 16 edges x 128 outs; l1 identity-MFMA P-sum; l2 fused; segsum
// via ballot+shuffles. Wave-synchronous LDS (own region) for l1->l2 handoff.
// ---------------------------------------------------------------------------
__global__ __launch_bounds__(256, 4) void edge_kernel(
    const int* __restrict__ srcp, const int* __restrict__ dstp,
    const int* __restrict__ eidx, const float* __restrict__ a,
    const float* __restrict__ coords,
    const unsigned short* __restrict__ Psc, const unsigned short* __restrict__ Pdc,
    const unsigned short* __restrict__ Pse, const unsigned short* __restrict__ Pde,
    const float* __restrict__ bc2, const float* __restrict__ Wc3,
    const float* __restrict__ be2,
    const float* __restrict__ Watt, const float* __restrict__ batt,
    const unsigned short* __restrict__ wpan,
    float* __restrict__ out_h, float* __restrict__ out_x)
{
    __shared__ __align__(16) unsigned short csh_c[4][WT][LPW];
    __shared__ __align__(16) unsigned short csh_e[4][WT][LPW];

    const int tid  = threadIdx.x;
    const int lane = tid & 63;
    const int w    = tid >> 6;
    const int col  = lane & 15;
    const int kg   = lane >> 4;
    const int e0   = (blockIdx.x * 4 + w) * WT;

    // ---- prologue (lanes<16 load per-edge data; broadcast via shuffles) ----
    int srcv = 0, dstv = 0, eidv = 0;
    float dfx = 0.f, dfy = 0.f, dfz = 0.f, radv = 0.f, rinvv = 0.f;
    if (lane < WT) {
        srcv = srcp[e0 + lane];
        dstv = dstp[e0 + lane];
        eidv = eidx[e0 + lane];
        const float sx = coords[(size_t)srcv*3+0], sy = coords[(size_t)srcv*3+1], sz = coords[(size_t)srcv*3+2];
        const float dx_ = coords[(size_t)dstv*3+0], dy_ = coords[(size_t)dstv*3+1], dz_ = coords[(size_t)dstv*3+2];
        dfx = sx - dx_; dfy = sy - dy_; dfz = sz - dz_;
        radv = dfx*dfx + dfy*dfy + dfz*dfz;
        rinvv = __builtin_amdgcn_rcpf(sqrtf(radv + 1e-5f) + 1.f);
    }
    const int   se    = __shfl(srcv, col);
    const int   de_   = __shfl(dstv, col);
    const int   ee    = __shfl(eidv, col);
    const float rad_c = __shfl(radv, col);

    // run boundaries (dst-sorted): mask uniform across wave
    const int prevd = __shfl_up(dstv, 1);
    const bool st = (lane < WT) && (lane == 0 || dstv != prevd);
    const unsigned long long mask = __ballot(st) & 0xffffull;

    // P-table fragment bases (kg<2 -> src tables, kg>=2 -> dst tables)
    const size_t so   = (size_t)se  * HD;
    const size_t dofs = (size_t)de_ * HD;
    const int slot = (kg & 1) * 8;
    const unsigned short* bas_c = ((kg < 2) ? Psc + so : Pdc + dofs) + slot;
    const unsigned short* bas_e = ((kg < 2) ? Pse + so : Pde + dofs) + slot;

    const unsigned short* Wc1p = wpan            + lane * 8;
    const unsigned short* We1p = wpan + O_WE1    + lane * 8;
    const unsigned short* Wc2p = wpan + O_WC2    + lane * 8;
    const unsigned short* We2p = wpan + O_WE2    + lane * 8;

    // identity A-fragment: A[o][k] = delta(k&15, o)
    short8 idf;
    #pragma unroll
    for (int j = 0; j < 8; ++j)
        idf[j] = (short)((((kg * 8 + j) & 15) == col) ? 0x3F80 : 0);

    const short8 zf = {0,0,0,0,0,0,0,0};
    const f32x4 zero = {0.f, 0.f, 0.f, 0.f};

    // a/rad/bias chunk (kc=8) data fragment
    short8 df;
    if (kg < 2) {
        const float4 a0 = *(const float4*)(a + (size_t)ee * EFD + kg * 8);
        const float4 a1 = *(const float4*)(a + (size_t)ee * EFD + kg * 8 + 4);
        df[0] = (short)f2bf(a0.x); df[1] = (short)f2bf(a0.y);
        df[2] = (short)f2bf(a0.z); df[3] = (short)f2bf(a0.w);
        df[4] = (short)f2bf(a1.x); df[5] = (short)f2bf(a1.y);
        df[6] = (short)f2bf(a1.z); df[7] = (short)f2bf(a1.w);
    } else if (kg == 2) {
        df = zf;
        df[0] = (short)f2bf(rad_c);
        df[1] = (short)0x3F80;
    } else df = zf;

    // ================= layer 1 (per-m: id-MFMA P-sum + a-chunk + store) =====
    #pragma unroll
    for (int m = 0; m < 8; ++m) {
        const short8 bc_ = *(const short8*)(bas_c + m * 16);
        const short8 be_ = *(const short8*)(bas_e + m * 16);
        f32x4 ac = __builtin_amdgcn_mfma_f32_16x16x32_bf16(idf, bc_, zero, 0, 0, 0);
        f32x4 ae = __builtin_amdgcn_mfma_f32_16x16x32_bf16(idf, be_, zero, 0, 0, 0);
        const short8 wc = *(const short8*)&Wc1p[(m * 9 + 8) << 9];
        const short8 we = *(const short8*)&We1p[(m * 9 + 8) << 9];
        ac = __builtin_amdgcn_mfma_f32_16x16x32_bf16(wc, df, ac, 0, 0, 0);
        ae = __builtin_amdgcn_mfma_f32_16x16x32_bf16(we, df, ae, 0, 0, 0);
        const int hw = m * 16 + kg * 4;
        uint2 vc, ve;
        vc.x = pack2(silu_f(ac[0]), silu_f(ac[1]));
        vc.y = pack2(silu_f(ac[2]), silu_f(ac[3]));
        ve.x = pack2(silu_f(ae[0]), silu_f(ae[1]));
        ve.y = pack2(silu_f(ae[2]), silu_f(ae[3]));
        *(uint2*)&csh_c[w][col][hw] = vc;
        *(uint2*)&csh_e[w][col][hw] = ve;
    }
    __builtin_amdgcn_wave_barrier();     // order l1 stores before l2 loads

    // ================= layer 2 =================
    short8 dc[4], de2[4];
    #pragma unroll
    for (int kc = 0; kc < 4; ++kc) {
        dc[kc]  = *(const short8*)&csh_c[w][col][kc * 32 + kg * 8];
        de2[kc] = *(const short8*)&csh_e[w][col][kc * 32 + kg * 8];
    }
    __builtin_amdgcn_wave_barrier();     // loads done before msg overwrites

    float scl = 0.f, pal = 0.f;
    #pragma unroll
    for (int m = 0; m < 8; ++m) {
        f32x4 ac = zero, ae = zero;
        #pragma unroll
        for (int kc = 0; kc < 4; ++kc) {
            const short8 wc = *(const short8*)&Wc2p[(m * 4 + kc) << 9];
            const short8 we = *(const short8*)&We2p[(m * 4 + kc) << 9];
            ac = __builtin_amdgcn_mfma_f32_16x16x32_bf16(wc, dc[kc],  ac, 0, 0, 0);
            ae = __builtin_amdgcn_mfma_f32_16x16x32_bf16(we, de2[kc], ae, 0, 0, 0);
        }
        const int hw = m * 16 + kg * 4;
        const float4 b2 = *(const float4*)(bc2 + hw);
        const float4 w3 = *(const float4*)(Wc3 + hw);
        scl += silu_f(ac[0] + b2.x) * w3.x + silu_f(ac[1] + b2.y) * w3.y
             + silu_f(ac[2] + b2.z) * w3.z + silu_f(ac[3] + b2.w) * w3.w;
        const float4 be_ = *(const float4*)(be2 + hw);
        const float4 wa  = *(const float4*)(Watt + hw);
        const float v0 = silu_f(ae[0] + be_.x);
        const float v1 = silu_f(ae[1] + be_.y);
        const float v2 = silu_f(ae[2] + be_.z);
        const float v3 = silu_f(ae[3] + be_.w);
        pal += v0 * wa.x + v1 * wa.y + v2 * wa.z + v3 * wa.w;
        uint2 ve;
        ve.x = pack2(v0, v1);
        ve.y = pack2(v2, v3);
        *(uint2*)&csh_e[w][col][hw] = ve;   // msg overwrites e1 (wave-sync OK)
    }
    __builtin_amdgcn_wave_barrier();     // msg stores before segsum reads

    // cross-kg reduction (lanes of same col)
    scl += __shfl_xor(scl, 16);
    scl += __shfl_xor(scl, 32);
    pal += __shfl_xor(pal, 16);
    pal += __shfl_xor(pal, 32);
    const float att_v = sigm_f(pal + batt[0]);     // valid per-col on all kg
    const float sc_v  = scl * __shfl(rinvv, col);  // rinv from lane col

    // ================= segmented sum (wave-local, shuffles) =================
    {
        unsigned long long mm = mask;
        while (mm) {
            const int s0 = (int)__builtin_ctzll(mm);
            mm &= mm - 1;
            const int s1 = mm ? (int)__builtin_ctzll(mm) : WT;
            float sum0 = 0.f, sum1 = 0.f, sx0 = 0.f, sx1 = 0.f;
            for (int e = s0; e < s1; ++e) {
                const unsigned uv = *(const unsigned*)&csh_e[w][e][lane * 2];
                const float at = __shfl(att_v, e);
                sum0 += bfl(uv) * at;
                sum1 += bfh(uv) * at;
                const float sce = __shfl(sc_v, e);
                const float d0 = __shfl(dfx, e);
                const float d1 = __shfl(dfy, e);
                const float d2 = __shfl(dfz, e);
                if (lane == 0) { sx0 += sce * d0; sx1 += sce * d1; }
                if (lane == 1) { sx0 += sce * d2; }
            }
            const int drow = __shfl(dstv, s0);
            float* op = out_h + (size_t)drow * HD + lane * 2;
            atomicAdd(op,     sum0);
            atomicAdd(op + 1, sum1);
            if (lane == 0) {
                atomicAdd(&out_x[(size_t)drow * 3 + 0], sx0);
                atomicAdd(&out_x[(size_t)drow * 3 + 1], sx1);
            }
            if (lane == 1) {
                atomicAdd(&out_x[(size_t)drow * 3 + 2], sx0);
            }
        }
    }
}

// ---------------------------------------------------------------------------
// Node kernel (unchanged)
// ---------------------------------------------------------------------------
__global__ __launch_bounds__(256) void node_kernel(
    const float* __restrict__ h, const float* __restrict__ coords,
    const float* __restrict__ bn1, const float* __restrict__ bn2,
    const unsigned short* __restrict__ wpan,
    float* __restrict__ out_h, float* __restrict__ out_x)
{
    __shared__ __align__(16) unsigned short ash[MT][LPA];
    __shared__ __align__(16) unsigned short csh[MT][LPC];

    const int tid = threadIdx.x;
    const int n0  = blockIdx.x * MT;

    #pragma unroll
    for (int it = 0; it < 16; ++it) {
        const int idx = it * 256 + tid;
        const int e = idx >> 6, q = idx & 63;
        const float* base = (q < 32)
            ? h     + (size_t)(n0 + e) * HD + q * 4
            : out_h + (size_t)(n0 + e) * HD + (q - 32) * 4;
        const float4 v = *(const float4*)base;
        uint2 p; p.x = pack2(v.x, v.y); p.y = pack2(v.z, v.w);
        *(uint2*)&ash[e][q * 4] = p;
    }
    __syncthreads();

    if (tid < MT * 3) {
        const int n = tid / 3, d = tid % 3;
        const size_t gi = (size_t)(n0 + n) * 3 + d;
        out_x[gi] += coords[gi];
    }

    const int lane = tid & 63;
    const int w    = tid >> 6;
    const int er0  = w * 16;
    const int col  = lane & 15;
    const int kg   = lane >> 4;

    const unsigned short* Wn1p = wpan + O_WN1 + lane * 8;
    const unsigned short* Wn2p = wpan + O_WN2 + lane * 8;

    const f32x4 zero = {0.f, 0.f, 0.f, 0.f};
    f32x4 acc[8];

    #pragma unroll
    for (int n = 0; n < 8; ++n) acc[n] = zero;
    #pragma unroll
    for (int kc = 0; kc < 8; ++kc) {
        const short8 af = *(const short8*)&ash[er0 + col][kc * 32 + kg * 8];
        #pragma unroll
        for (int n = 0; n < 8; ++n) {
            const short8 bf = *(const short8*)&Wn1p[(n * 8 + kc) << 9];
            acc[n] = __builtin_amdgcn_mfma_f32_16x16x32_bf16(af, bf, acc[n], 0, 0, 0);
        }
    }
    #pragma unroll
    for (int n = 0; n < 8; ++n) {
        const float b = bn1[n*16 + col];
        #pragma unroll
        for (int i = 0; i < 4; ++i)
            csh[er0 + kg*4 + i][n*16 + col] = f2bf(silu_f(acc[n][i] + b));
    }
    __syncthreads();
    #pragma unroll
    for (int n = 0; n < 8; ++n) acc[n] = zero;
    #pragma unroll
    for (int kc = 0; kc < 4; ++kc) {
        const short8 af = *(const short8*)&csh[er0 + col][kc * 32 + kg * 8];
        #pragma unroll
        for (int n = 0; n < 8; ++n) {
            const short8 bf = *(const short8*)&Wn2p[(n * 4 + kc) << 9];
            acc[n] = __builtin_amdgcn_mfma_f32_16x16x32_bf16(af, bf, acc[n], 0, 0, 0);
        }
    }
    #pragma unroll
    for (int i = 0; i < 4; ++i) {
        const int node = n0 + er0 + kg*4 + i;
        const float* hr   = h     + (size_t)node * HD;
        float*       orow = out_h + (size_t)node * HD;
        #pragma unroll
        for (int n = 0; n < 8; ++n) {
            const int f = n*16 + col;
            orow[f] = hr[f] + acc[n][i] + bn2[f];
        }
    }
}

extern "C" void kernel_launch(void* const* d_in, const int* in_sizes, int n_in,
                              void* d_out, int out_size, void* d_ws, size_t ws_size,
                              hipStream_t stream)
{
    const int*   src    = (const int*)  d_in[0];
    const int*   dst    = (const int*)  d_in[1];
    const float* h      = (const float*)d_in[2];
    const float* coords = (const float*)d_in[3];
    const float* a      = (const float*)d_in[4];
    const float* Wc1    = (const float*)d_in[5];
    const float* bc1    = (const float*)d_in[6];
    const float* Wc2    = (const float*)d_in[7];
    const float* bc2    = (const float*)d_in[8];
    const float* Wc3    = (const float*)d_in[9];
    const float* We1    = (const float*)d_in[10];
    const float* be1    = (const float*)d_in[11];
    const float* We2    = (const float*)d_in[12];
    const float* be2    = (const float*)d_in[13];
    const float* Watt   = (const float*)d_in[14];
    const float* batt   = (const float*)d_in[15];
    const float* Wn1    = (const float*)d_in[16];
    const float* bn1    = (const float*)d_in[17];
    const float* Wn2    = (const float*)d_in[18];
    const float* bn2    = (const float*)d_in[19];

    const int E = in_sizes[0];
    const int N = in_sizes[2] / HD;

    float* out_h = (float*)d_out;
    float* out_x = out_h + (size_t)N * HD;

    char* wsb = (char*)d_ws;
    unsigned short* Psc  = (unsigned short*)(wsb + B_PSC);
    unsigned short* Pdc  = (unsigned short*)(wsb + B_PDC);
    unsigned short* Pse  = (unsigned short*)(wsb + B_PSE);
    unsigned short* Pde  = (unsigned short*)(wsb + B_PDE);
    unsigned short* wpan = (unsigned short*)(wsb + B_WPAN);
    unsigned*       cnt  = (unsigned*)      (wsb + B_CNT);
    unsigned*       ofs  = (unsigned*)      (wsb + B_OFS);
    int*            srcp = (int*)           (wsb + B_SRCP);
    int*            dstp = (int*)           (wsb + B_DSTP);
    int*            eidx = (int*)           (wsb + B_EIDX);

    hipMemsetAsync(d_out, 0, (size_t)out_size * sizeof(float), stream);
    hipMemsetAsync(cnt, 0, (size_t)N * sizeof(unsigned), stream);

    const int nPrep = WS_ELEMS / 256;              // 608
    const int nHist = (E + 255) / 256;             // 2048

    fused_prep<<<dim3(nPrep + nHist), dim3(256), 0, stream>>>(
        Wc1, bc1, We1, be1, Wc2, We2, Wn1, Wn2, wpan,
        dst, cnt, nPrep, E);

    node_pre<<<dim3(N / MT), dim3(256), 0, stream>>>(
        h, wpan, Psc, Pdc, Pse, Pde);

    scan32k<<<dim3(1), dim3(1024), 0, stream>>>(cnt, ofs);
    scatter_perm<<<dim3((E + 255) / 256), dim3(256), 0, stream>>>(
        src, dst, ofs, srcp, dstp, eidx, E);

    edge_kernel<<<dim3(E / (4 * WT)), dim3(256), 0, stream>>>(
        srcp, dstp, eidx, a, coords,
        Psc, Pdc, Pse, Pde,
        bc2, Wc3, be2, Watt, batt,
        wpan, out_h, out_x);

    node_kernel<<<dim3(N / MT), dim3(256), 0, stream>>>(
        h, coords, bn1, bn2, wpan, out_h, out_x);
}

// Round 15
// 307.135 us; speedup vs baseline: 1.1474x; 1.1474x over previous
//
#include <hip/hip_runtime.h>
#include <math.h>

#define HD   128
#define EFD  16
#define MT   64      // node-kernel tile
#define MTE  32      // edge-kernel tile
#define LPA  264
#define LPC  136     // LDS pitch (ushort): rows, cols=128+pad

#define W1SZ (128 * 288)
#define W2SZ (128 * 128)
#define O_WE1 (W1SZ)
#define O_WC2 (2 * W1SZ)
#define O_WE2 (2 * W1SZ + W2SZ)
#define O_WN1 (2 * W1SZ + 2 * W2SZ)
#define O_WN2 (2 * W1SZ + 2 * W2SZ + 128 * 256)
#define WS_ELEMS (O_WN2 + W2SZ)          // 155648

// ws byte layout (~40.4 MB)
#define B_PSC   ((size_t)0)
#define B_PDC   ((size_t)8388608)
#define B_PSE   ((size_t)16777216)
#define B_PDE   ((size_t)25165824)
#define B_WPAN  ((size_t)33554432)
#define B_CNT   ((size_t)33865728)
#define B_OFS   ((size_t)33996800)
#define B_SRCP  ((size_t)34127872)
#define B_DSTP  ((size_t)36225024)
#define B_EIDX  ((size_t)38322176)

typedef __attribute__((ext_vector_type(8))) short short8;
typedef __attribute__((ext_vector_type(4))) float f32x4;

__device__ __forceinline__ unsigned short f2bf(float x) {
    __bf16 b = (__bf16)x;
    unsigned short u;
    __builtin_memcpy(&u, &b, 2);
    return u;
}
__device__ __forceinline__ float bfl(unsigned u) {
    union { unsigned u; float f; } v; v.u = u << 16; return v.f;
}
__device__ __forceinline__ float bfh(unsigned u) {
    union { unsigned u; float f; } v; v.u = u & 0xffff0000u; return v.f;
}
__device__ __forceinline__ float sigm_f(float x) {
    return __builtin_amdgcn_rcpf(1.f + __expf(-x));
}
__device__ __forceinline__ float silu_f(float x) { return x * sigm_f(x); }
__device__ __forceinline__ unsigned pack2(float a, float b) {
    return (unsigned)f2bf(a) | ((unsigned)f2bf(b) << 16);
}

// ---------------------------------------------------------------------------
// Fragment-ordered bf16 weight panels (A-operand layout).
// ---------------------------------------------------------------------------
__device__ __forceinline__ void frag_l1(int idx, const float* __restrict__ W,
                                        const float* __restrict__ bias,
                                        unsigned short* __restrict__ out)
{
    const int j = idx & 7, lane = (idx >> 3) & 63, blk = idx >> 9;
    const int kc = blk % 9, n = blk / 9;
    const int k = kc * 32 + (lane >> 4) * 8 + j;
    const int c = n * 16 + (lane & 15);
    float v = 0.f;
    if (k < 256) v = W[k * HD + c];
    else if (k < 272) v = W[(k + 1) * HD + c];
    else if (k == 272) v = W[256 * HD + c];
    else if (k == 273) v = bias[c];
    out[idx] = f2bf(v);
}
__device__ __forceinline__ void frag_sq(int idx, const float* __restrict__ W,
                                        int nkc, unsigned short* __restrict__ out)
{
    const int j = idx & 7, lane = (idx >> 3) & 63, blk = idx >> 9;
    const int kc = blk % nkc, n = blk / nkc;
    const int k = kc * 32 + (lane >> 4) * 8 + j;
    const int c = n * 16 + (lane & 15);
    out[idx] = f2bf(W[k * HD + c]);
}

__global__ __launch_bounds__(256) void fused_prep(
    const float* __restrict__ Wc1, const float* __restrict__ bc1,
    const float* __restrict__ We1, const float* __restrict__ be1,
    const float* __restrict__ Wc2, const float* __restrict__ We2,
    const float* __restrict__ Wn1, const float* __restrict__ Wn2,
    unsigned short* __restrict__ ws,
    const int* __restrict__ dst, unsigned* __restrict__ cnt,
    int nPrep, int E)
{
    const int bid = blockIdx.x, tid = threadIdx.x;
    if (bid < nPrep) {
        int idx = bid * 256 + tid;
        if (idx < W1SZ)            { frag_l1(idx, Wc1, bc1, ws);            return; }
        idx -= W1SZ;
        if (idx < W1SZ)            { frag_l1(idx, We1, be1, ws + O_WE1);    return; }
        idx -= W1SZ;
        if (idx < W2SZ)            { frag_sq(idx, Wc2, 4, ws + O_WC2);      return; }
        idx -= W2SZ;
        if (idx < W2SZ)            { frag_sq(idx, We2, 4, ws + O_WE2);      return; }
        idx -= W2SZ;
        if (idx < 128 * 256)       { frag_sq(idx, Wn1, 8, ws + O_WN1);      return; }
        idx -= 128 * 256;
        if (idx < W2SZ)            { frag_sq(idx, Wn2, 4, ws + O_WN2); }
        return;
    }
    const int i = (bid - nPrep) * 256 + tid;
    if (i < E) atomicAdd(&cnt[dst[i]], 1u);
}

// ---------------------------------------------------------------------------
// node_pre: P tables = h @ W1-halves
// ---------------------------------------------------------------------------
__device__ __forceinline__ void pre_pass(
    const unsigned short* __restrict__ panelp,
    const unsigned short* __restrict__ hsh,
    unsigned short* __restrict__ Ps, unsigned short* __restrict__ Pd,
    int n0, int w2, int w, int col, int kg)
{
    const f32x4 zero = {0.f, 0.f, 0.f, 0.f};
    f32x4 as_[2][4], ad_[2][4];
    #pragma unroll
    for (int m = 0; m < 2; ++m)
        #pragma unroll
        for (int et = 0; et < 4; ++et) { as_[m][et] = zero; ad_[m][et] = zero; }
    #pragma unroll
    for (int kc = 0; kc < 4; ++kc) {
        short8 bf[4];
        #pragma unroll
        for (int et = 0; et < 4; ++et)
            bf[et] = *(const short8*)&hsh[(et*16 + col) * LPC + kc * 32 + kg * 8];
        #pragma unroll
        for (int m = 0; m < 2; ++m) {
            const short8 As = *(const short8*)&panelp[((w2 + m) * 9 + kc) << 9];
            const short8 Ad = *(const short8*)&panelp[((w2 + m) * 9 + kc + 4) << 9];
            #pragma unroll
            for (int et = 0; et < 4; ++et) {
                as_[m][et] = __builtin_amdgcn_mfma_f32_16x16x32_bf16(As, bf[et], as_[m][et], 0, 0, 0);
                ad_[m][et] = __builtin_amdgcn_mfma_f32_16x16x32_bf16(Ad, bf[et], ad_[m][et], 0, 0, 0);
            }
        }
    }
    #pragma unroll
    for (int m = 0; m < 2; ++m)
        #pragma unroll
        for (int et = 0; et < 4; ++et) {
            const size_t row = (size_t)(n0 + et * 16 + col) * HD;
            const int hw = w * 32 + m * 16 + kg * 4;
            uint2 vs, vd;
            vs.x = pack2(as_[m][et][0], as_[m][et][1]);
            vs.y = pack2(as_[m][et][2], as_[m][et][3]);
            vd.x = pack2(ad_[m][et][0], ad_[m][et][1]);
            vd.y = pack2(ad_[m][et][2], ad_[m][et][3]);
            *(uint2*)(Ps + row + hw) = vs;
            *(uint2*)(Pd + row + hw) = vd;
        }
}

__global__ __launch_bounds__(256) void node_pre(
    const float* __restrict__ h, const unsigned short* __restrict__ wpan,
    unsigned short* __restrict__ Psc, unsigned short* __restrict__ Pdc,
    unsigned short* __restrict__ Pse, unsigned short* __restrict__ Pde)
{
    __shared__ __align__(16) unsigned short hsh[MT][LPC];
    const int tid = threadIdx.x;
    const int n0  = blockIdx.x * MT;

    #pragma unroll
    for (int it = 0; it < 8; ++it) {
        const int idx = it * 256 + tid;
        const int r = idx >> 5, q = idx & 31;
        const float4 v = *(const float4*)(h + (size_t)(n0 + r) * HD + q * 4);
        uint2 p; p.x = pack2(v.x, v.y); p.y = pack2(v.z, v.w);
        *(uint2*)&hsh[r][q * 4] = p;
    }
    __syncthreads();

    const int lane = tid & 63;
    const int w    = tid >> 6;
    const int w2   = w * 2;
    const int col  = lane & 15;
    const int kg   = lane >> 4;

    pre_pass(wpan + lane * 8,         &hsh[0][0], Psc, Pdc, n0, w2, w, col, kg);
    pre_pass(wpan + O_WE1 + lane * 8, &hsh[0][0], Pse, Pde, n0, w2, w, col, kg);
}

// ---------------------------------------------------------------------------
__global__ __launch_bounds__(1024) void scan32k(const unsigned* __restrict__ cnt,
                                                unsigned* __restrict__ ofs)
{
    __shared__ unsigned wsum[16];
    __shared__ unsigned carry_s;
    const int tid = threadIdx.x, lane = tid & 63, w = tid >> 6;
    if (tid == 0) carry_s = 0;
    __syncthreads();
    for (int c = 0; c < 32; ++c) {
        const unsigned x = cnt[c * 1024 + tid];
        unsigned v = x;
        #pragma unroll
        for (int off = 1; off < 64; off <<= 1) {
            unsigned t = __shfl_up(v, off);
            if (lane >= off) v += t;
        }
        if (lane == 63) wsum[w] = v;
        __syncthreads();
        if (tid < 16) {
            unsigned s = wsum[tid];
            #pragma unroll
            for (int off = 1; off < 16; off <<= 1) {
                unsigned t = __shfl_up(s, off);
                if (tid >= off) s += t;
            }
            wsum[tid] = s;
        }
        __syncthreads();
        const unsigned carry = carry_s;
        const unsigned woff = (w == 0) ? 0u : wsum[w - 1];
        ofs[c * 1024 + tid] = carry + woff + v - x;
        __syncthreads();
        if (tid == 0) carry_s = carry + wsum[15];
        __syncthreads();
    }
}

__global__ __launch_bounds__(256) void scatter_perm(
    const int* __restrict__ src, const int* __restrict__ dst,
    unsigned* __restrict__ ofs,
    int* __restrict__ srcp, int* __restrict__ dstp,
    int* __restrict__ eidx, int E)
{
    const int i = blockIdx.x * 256 + threadIdx.x;
    if (i >= E) return;
    const int d = dst[i];
    const unsigned pos = atomicAdd(&ofs[d], 1u);
    srcp[pos] = src[i];
    dstp[pos] = d;
    eidx[pos] = i;
}

// ---------------------------------------------------------------------------
// Edge kernel, MTE=32 tile (round-13 structure) + float4 epilogue params.
// ---------------------------------------------------------------------------
__global__ __launch_bounds__(256, 4) void edge_kernel(
    const int* __restrict__ srcp, const int* __restrict__ dstp,
    const int* __restrict__ eidx, const float* __restrict__ a,
    const float* __restrict__ coords,
    const unsigned short* __restrict__ Psc, const unsigned short* __restrict__ Pdc,
    const unsigned short* __restrict__ Pse, const unsigned short* __restrict__ Pde,
    const float* __restrict__ bc2, const float* __restrict__ Wc3,
    const float* __restrict__ be2,
    const float* __restrict__ Watt, const float* __restrict__ batt,
    const unsigned short* __restrict__ wpan,
    float* __restrict__ out_h, float* __restrict__ out_x)
{
    __shared__ __align__(16) unsigned short csh_c[MTE][LPC];
    __shared__ __align__(16) unsigned short csh_e[MTE][LPC];
    __shared__ float diff_s[MTE][3];
    __shared__ float rad_s[MTE];
    __shared__ float rinv_s[MTE];
    __shared__ float sc_part[4][MTE];
    __shared__ float pa_part[4][MTE];
    __shared__ float att_s[MTE];
    __shared__ float sc_s[MTE];
    __shared__ int   src_s[MTE], dst_s[MTE], eid_s[MTE];
    __shared__ short run_start[MTE + 2];
    __shared__ int   nruns_s;

    const int tid = threadIdx.x;
    const int e0  = blockIdx.x * MTE;

    if (tid < MTE) {
        const int s = srcp[e0 + tid], d = dstp[e0 + tid];
        src_s[tid] = s; dst_s[tid] = d;
        eid_s[tid] = eidx[e0 + tid];
        const float dx = coords[(size_t)s*3+0] - coords[(size_t)d*3+0];
        const float dy = coords[(size_t)s*3+1] - coords[(size_t)d*3+1];
        const float dz = coords[(size_t)s*3+2] - coords[(size_t)d*3+2];
        diff_s[tid][0] = dx; diff_s[tid][1] = dy; diff_s[tid][2] = dz;
        const float rad = dx*dx + dy*dy + dz*dz;
        rad_s[tid]  = rad;
        rinv_s[tid] = __builtin_amdgcn_rcpf(sqrtf(rad + 1e-5f) + 1.f);
    }
    __syncthreads();                                     // Ba

    if (tid < MTE) {
        const bool st = (tid == 0) || (dst_s[tid] != dst_s[tid - 1]);
        unsigned long long m = __ballot(st);
        if (tid == 0) {
            int nr = 0;
            while (m) { run_start[nr++] = (short)__builtin_ctzll(m); m &= m - 1; }
            run_start[nr] = MTE;
            nruns_s = nr;
        }
    }

    const int lane = tid & 63;
    const int w    = tid >> 6;        // out-col quarter
    const int w2   = w * 2;
    const int col  = lane & 15;       // edge within 16-tile
    const int kg   = lane >> 4;

    const unsigned short* Wc1p = wpan            + lane * 8;
    const unsigned short* We1p = wpan + O_WE1    + lane * 8;
    const unsigned short* Wc2p = wpan + O_WC2    + lane * 8;
    const unsigned short* We2p = wpan + O_WE2    + lane * 8;

    // identity A-fragment: A[o][k] = delta(k&15, o)
    short8 idf;
    #pragma unroll
    for (int j = 0; j < 8; ++j)
        idf[j] = (short)((((kg * 8 + j) & 15) == col) ? 0x3F80 : 0);

    // per-(et) B-fragment bases: kg<2 lanes read Ps (src), kg>=2 read Pd (dst)
    const unsigned short* bas_c[2];
    const unsigned short* bas_e[2];
    #pragma unroll
    for (int et = 0; et < 2; ++et) {
        const int r = et * 16 + col;
        const size_t so   = (size_t)src_s[r] * HD;
        const size_t dofs = (size_t)dst_s[r] * HD;
        const int slot = (kg & 1) * 8;
        bas_c[et] = ((kg < 2) ? Psc + so : Pdc + dofs) + slot;
        bas_e[et] = ((kg < 2) ? Pse + so : Pde + dofs) + slot;
    }

    const short8 zf = {0,0,0,0,0,0,0,0};
    const f32x4 zero = {0.f, 0.f, 0.f, 0.f};
    f32x4 ac[2][2], ae[2][2];

    // ============ layer 1: identity-MFMA P-sum + (a,rad,bias) chunk =========
    #pragma unroll
    for (int m = 0; m < 2; ++m)
        #pragma unroll
        for (int et = 0; et < 2; ++et) { ac[m][et] = zero; ae[m][et] = zero; }

    #pragma unroll
    for (int m = 0; m < 2; ++m) {
        const int co = (w2 + m) * 16;
        #pragma unroll
        for (int et = 0; et < 2; ++et) {
            const short8 bc_ = *(const short8*)(bas_c[et] + co);
            const short8 be_ = *(const short8*)(bas_e[et] + co);
            ac[m][et] = __builtin_amdgcn_mfma_f32_16x16x32_bf16(idf, bc_, ac[m][et], 0, 0, 0);
            ae[m][et] = __builtin_amdgcn_mfma_f32_16x16x32_bf16(idf, be_, ae[m][et], 0, 0, 0);
        }
    }
    {   // kc=8 chunk: a(16) | rad | 1.0(bias) | pad
        short8 df[2];
        #pragma unroll
        for (int et = 0; et < 2; ++et) {
            if (kg < 2) {
                const int oe = eid_s[et * 16 + col];
                const float4 a0 = *(const float4*)(a + (size_t)oe * EFD + kg * 8);
                const float4 a1 = *(const float4*)(a + (size_t)oe * EFD + kg * 8 + 4);
                short8 v;
                v[0] = (short)f2bf(a0.x); v[1] = (short)f2bf(a0.y);
                v[2] = (short)f2bf(a0.z); v[3] = (short)f2bf(a0.w);
                v[4] = (short)f2bf(a1.x); v[5] = (short)f2bf(a1.y);
                v[6] = (short)f2bf(a1.z); v[7] = (short)f2bf(a1.w);
                df[et] = v;
            } else if (kg == 2) {
                short8 v = zf;
                v[0] = (short)f2bf(rad_s[et * 16 + col]);
                v[1] = (short)0x3F80;
                df[et] = v;
            } else df[et] = zf;
        }
        #pragma unroll
        for (int m = 0; m < 2; ++m) {
            const short8 wc = *(const short8*)&Wc1p[((w2 + m) * 9 + 8) << 9];
            const short8 we = *(const short8*)&We1p[((w2 + m) * 9 + 8) << 9];
            #pragma unroll
            for (int et = 0; et < 2; ++et) {
                ac[m][et] = __builtin_amdgcn_mfma_f32_16x16x32_bf16(wc, df[et], ac[m][et], 0, 0, 0);
                ae[m][et] = __builtin_amdgcn_mfma_f32_16x16x32_bf16(we, df[et], ae[m][et], 0, 0, 0);
            }
        }
    }
    // epilogue: silu -> packed b64 stores
    #pragma unroll
    for (int m = 0; m < 2; ++m)
        #pragma unroll
        for (int et = 0; et < 2; ++et) {
            const int row = et * 16 + col;
            const int hw  = w * 32 + m * 16 + kg * 4;
            uint2 vc, ve;
            vc.x = pack2(silu_f(ac[m][et][0]), silu_f(ac[m][et][1]));
            vc.y = pack2(silu_f(ac[m][et][2]), silu_f(ac[m][et][3]));
            ve.x = pack2(silu_f(ae[m][et][0]), silu_f(ae[m][et][1]));
            ve.y = pack2(silu_f(ae[m][et][2]), silu_f(ae[m][et][3]));
            *(uint2*)&csh_c[row][hw] = vc;
            *(uint2*)&csh_e[row][hw] = ve;
        }
    __syncthreads();                                     // B1

    // ================= layer 2 (coord + edge fused) =================
    #pragma unroll
    for (int m = 0; m < 2; ++m)
        #pragma unroll
        for (int et = 0; et < 2; ++et) { ac[m][et] = zero; ae[m][et] = zero; }

    #pragma unroll
    for (int kc = 0; kc < 4; ++kc) {
        short8 dc[2], de[2];
        #pragma unroll
        for (int et = 0; et < 2; ++et) {
            const int row = et * 16 + col;
            dc[et] = *(const short8*)&csh_c[row][kc * 32 + kg * 8];
            de[et] = *(const short8*)&csh_e[row][kc * 32 + kg * 8];
        }
        #pragma unroll
        for (int m = 0; m < 2; ++m) {
            const short8 wc = *(const short8*)&Wc2p[((w2 + m) * 4 + kc) << 9];
            const short8 we = *(const short8*)&We2p[((w2 + m) * 4 + kc) << 9];
            #pragma unroll
            for (int et = 0; et < 2; ++et) {
                ac[m][et] = __builtin_amdgcn_mfma_f32_16x16x32_bf16(wc, dc[et], ac[m][et], 0, 0, 0);
                ae[m][et] = __builtin_amdgcn_mfma_f32_16x16x32_bf16(we, de[et], ae[m][et], 0, 0, 0);
            }
        }
    }

    {   // scale partial: float4 params, lane-local + kg reduce
        float sc[2] = {0.f, 0.f};
        #pragma unroll
        for (int m = 0; m < 2; ++m) {
            const int hw = w * 32 + m * 16 + kg * 4;
            const float4 b2 = *(const float4*)(bc2 + hw);
            const float4 w3 = *(const float4*)(Wc3 + hw);
            #pragma unroll
            for (int et = 0; et < 2; ++et) {
                sc[et] += silu_f(ac[m][et][0] + b2.x) * w3.x
                        + silu_f(ac[m][et][1] + b2.y) * w3.y
                        + silu_f(ac[m][et][2] + b2.z) * w3.z
                        + silu_f(ac[m][et][3] + b2.w) * w3.w;
            }
        }
        #pragma unroll
        for (int et = 0; et < 2; ++et) {
            sc[et] += __shfl_xor(sc[et], 16);
            sc[et] += __shfl_xor(sc[et], 32);
        }
        if (kg == 0) {
            #pragma unroll
            for (int et = 0; et < 2; ++et)
                sc_part[w][et * 16 + col] = sc[et];
        }
    }
    __syncthreads();                                     // B2

    {   // msg epilogue: float4 params, b64 store + att partial
        float pa[2] = {0.f, 0.f};
        #pragma unroll
        for (int m = 0; m < 2; ++m) {
            const int hw = w * 32 + m * 16 + kg * 4;
            const float4 b2 = *(const float4*)(be2 + hw);
            const float4 wa = *(const float4*)(Watt + hw);
            #pragma unroll
            for (int et = 0; et < 2; ++et) {
                const int row = et * 16 + col;
                const float v0 = silu_f(ae[m][et][0] + b2.x);
                const float v1 = silu_f(ae[m][et][1] + b2.y);
                const float v2 = silu_f(ae[m][et][2] + b2.z);
                const float v3 = silu_f(ae[m][et][3] + b2.w);
                pa[et] += v0 * wa.x + v1 * wa.y + v2 * wa.z + v3 * wa.w;
                uint2 ve;
                ve.x = pack2(v0, v1);
                ve.y = pack2(v2, v3);
                *(uint2*)&csh_e[row][hw] = ve;
            }
        }
        #pragma unroll
        for (int et = 0; et < 2; ++et) {
            pa[et] += __shfl_xor(pa[et], 16);
            pa[et] += __shfl_xor(pa[et], 32);
        }
        if (kg == 0) {
            #pragma unroll
            for (int et = 0; et < 2; ++et)
                pa_part[w][et * 16 + col] = pa[et];
        }
    }
    __syncthreads();                                     // B3

    if (tid < MTE) {
        att_s[tid] = sigm_f(pa_part[0][tid] + pa_part[1][tid] +
                            pa_part[2][tid] + pa_part[3][tid] + batt[0]);
        sc_s[tid]  = (sc_part[0][tid] + sc_part[1][tid] +
                      sc_part[2][tid] + sc_part[3][tid]) * rinv_s[tid];
    }
    __syncthreads();                                     // B4

    // ---- segmented sum: dword reads (2 cols/thread), 4 run-groups ----
    {
        const int nr    = nruns_s;
        const int colx2 = tid & 63;
        for (int r = tid >> 6; r < nr; r += 4) {
            const int s0 = run_start[r], s1 = run_start[r + 1];
            float sum0 = 0.f, sum1 = 0.f;
            for (int e = s0; e < s1; ++e) {
                const unsigned uv = *(const unsigned*)&csh_e[e][colx2 * 2];
                const float at = att_s[e];
                sum0 += bfl(uv) * at;
                sum1 += bfh(uv) * at;
            }
            const int drow = dst_s[s0];
            float* op = out_h + (size_t)drow * HD + colx2 * 2;
            atomicAdd(op,     sum0);
            atomicAdd(op + 1, sum1);
            if (colx2 < 2) {
                float sx0 = 0.f, sx1 = 0.f;
                for (int e = s0; e < s1; ++e) {
                    const float s = sc_s[e];
                    sx0 += s * diff_s[e][colx2 * 2];
                    if (colx2 == 0) sx1 += s * diff_s[e][1];
                }
                atomicAdd(&out_x[(size_t)drow * 3 + colx2 * 2], sx0);
                if (colx2 == 0) atomicAdd(&out_x[(size_t)drow * 3 + 1], sx1);
            }
        }
    }
}

// ---------------------------------------------------------------------------
// Node kernel (unchanged)
// ---------------------------------------------------------------------------
__global__ __launch_bounds__(256) void node_kernel(
    const float* __restrict__ h, const float* __restrict__ coords,
    const float* __restrict__ bn1, const float* __restrict__ bn2,
    const unsigned short* __restrict__ wpan,
    float* __restrict__ out_h, float* __restrict__ out_x)
{
    __shared__ __align__(16) unsigned short ash[MT][LPA];
    __shared__ __align__(16) unsigned short csh[MT][LPC];

    const int tid = threadIdx.x;
    const int n0  = blockIdx.x * MT;

    #pragma unroll
    for (int it = 0; it < 16; ++it) {
        const int idx = it * 256 + tid;
        const int e = idx >> 6, q = idx & 63;
        const float* base = (q < 32)
            ? h     + (size_t)(n0 + e) * HD + q * 4
            : out_h + (size_t)(n0 + e) * HD + (q - 32) * 4;
        const float4 v = *(const float4*)base;
        uint2 p; p.x = pack2(v.x, v.y); p.y = pack2(v.z, v.w);
        *(uint2*)&ash[e][q * 4] = p;
    }
    __syncthreads();

    if (tid < MT * 3) {
        const int n = tid / 3, d = tid % 3;
        const size_t gi = (size_t)(n0 + n) * 3 + d;
        out_x[gi] += coords[gi];
    }

    const int lane = tid & 63;
    const int w    = tid >> 6;
    const int er0  = w * 16;
    const int col  = lane & 15;
    const int kg   = lane >> 4;

    const unsigned short* Wn1p = wpan + O_WN1 + lane * 8;
    const unsigned short* Wn2p = wpan + O_WN2 + lane * 8;

    const f32x4 zero = {0.f, 0.f, 0.f, 0.f};
    f32x4 acc[8];

    #pragma unroll
    for (int n = 0; n < 8; ++n) acc[n] = zero;
    #pragma unroll
    for (int kc = 0; kc < 8; ++kc) {
        const short8 af = *(const short8*)&ash[er0 + col][kc * 32 + kg * 8];
        #pragma unroll
        for (int n = 0; n < 8; ++n) {
            const short8 bf = *(const short8*)&Wn1p[(n * 8 + kc) << 9];
            acc[n] = __builtin_amdgcn_mfma_f32_16x16x32_bf16(af, bf, acc[n], 0, 0, 0);
        }
    }
    #pragma unroll
    for (int n = 0; n < 8; ++n) {
        const float b = bn1[n*16 + col];
        #pragma unroll
        for (int i = 0; i < 4; ++i)
            csh[er0 + kg*4 + i][n*16 + col] = f2bf(silu_f(acc[n][i] + b));
    }
    __syncthreads();
    #pragma unroll
    for (int n = 0; n < 8; ++n) acc[n] = zero;
    #pragma unroll
    for (int kc = 0; kc < 4; ++kc) {
        const short8 af = *(const short8*)&csh[er0 + col][kc * 32 + kg * 8];
        #pragma unroll
        for (int n = 0; n < 8; ++n) {
            const short8 bf = *(const short8*)&Wn2p[(n * 4 + kc) << 9];
            acc[n] = __builtin_amdgcn_mfma_f32_16x16x32_bf16(af, bf, acc[n], 0, 0, 0);
        }
    }
    #pragma unroll
    for (int i = 0; i < 4; ++i) {
        const int node = n0 + er0 + kg*4 + i;
        const float* hr   = h     + (size_t)node * HD;
        float*       orow = out_h + (size_t)node * HD;
        #pragma unroll
        for (int n = 0; n < 8; ++n) {
            const int f = n*16 + col;
            orow[f] = hr[f] + acc[n][i] + bn2[f];
        }
    }
}

extern "C" void kernel_launch(void* const* d_in, const int* in_sizes, int n_in,
                              void* d_out, int out_size, void* d_ws, size_t ws_size,
                              hipStream_t stream)
{
    const int*   src    = (const int*)  d_in[0];
    const int*   dst    = (const int*)  d_in[1];
    const float* h      = (const float*)d_in[2];
    const float* coords = (const float*)d_in[3];
    const float* a      = (const float*)d_in[4];
    const float* Wc1    = (const float*)d_in[5];
    const float* bc1    = (const float*)d_in[6];
    const float* Wc2    = (const float*)d_in[7];
    const float* bc2    = (const float*)d_in[8];
    const float* Wc3    = (const float*)d_in[9];
    const float* We1    = (const float*)d_in[10];
    const float* be1    = (const float*)d_in[11];
    const float* We2    = (const float*)d_in[12];
    const float* be2    = (const float*)d_in[13];
    const float* Watt   = (const float*)d_in[14];
    const float* batt   = (const float*)d_in[15];
    const float* Wn1    = (const float*)d_in[16];
    const float* bn1    = (const float*)d_in[17];
    const float* Wn2    = (const float*)d_in[18];
    const float* bn2    = (const float*)d_in[19];

    const int E = in_sizes[0];
    const int N = in_sizes[2] / HD;

    float* out_h = (float*)d_out;
    float* out_x = out_h + (size_t)N * HD;

    char* wsb = (char*)d_ws;
    unsigned short* Psc  = (unsigned short*)(wsb + B_PSC);
    unsigned short* Pdc  = (unsigned short*)(wsb + B_PDC);
    unsigned short* Pse  = (unsigned short*)(wsb + B_PSE);
    unsigned short* Pde  = (unsigned short*)(wsb + B_PDE);
    unsigned short* wpan = (unsigned short*)(wsb + B_WPAN);
    unsigned*       cnt  = (unsigned*)      (wsb + B_CNT);
    unsigned*       ofs  = (unsigned*)      (wsb + B_OFS);
    int*            srcp = (int*)           (wsb + B_SRCP);
    int*            dstp = (int*)           (wsb + B_DSTP);
    int*            eidx = (int*)           (wsb + B_EIDX);

    hipMemsetAsync(d_out, 0, (size_t)out_size * sizeof(float), stream);
    hipMemsetAsync(cnt, 0, (size_t)N * sizeof(unsigned), stream);

    const int nPrep = WS_ELEMS / 256;              // 608
    const int nHist = (E + 255) / 256;             // 2048

    fused_prep<<<dim3(nPrep + nHist), dim3(256), 0, stream>>>(
        Wc1, bc1, We1, be1, Wc2, We2, Wn1, Wn2, wpan,
        dst, cnt, nPrep, E);

    node_pre<<<dim3(N / MT), dim3(256), 0, stream>>>(
        h, wpan, Psc, Pdc, Pse, Pde);

    scan32k<<<dim3(1), dim3(1024), 0, stream>>>(cnt, ofs);
    scatter_perm<<<dim3((E + 255) / 256), dim3(256), 0, stream>>>(
        src, dst, ofs, srcp, dstp, eidx, E);

    edge_kernel<<<dim3(E / MTE), dim3(256), 0, stream>>>(
        srcp, dstp, eidx, a, coords,
        Psc, Pdc, Pse, Pde,
        bc2, Wc3, be2, Watt, batt,
        wpan, out_h, out_x);

    node_kernel<<<dim3(N / MT), dim3(256), 0, stream>>>(
        h, coords, bn1, bn2, wpan, out_h, out_x);
}